// Round 1
// baseline (59.692 us; speedup 1.0000x reference)
//
#include <hip/hip_runtime.h>
#include <math.h>

#define MARGIN 5.0f
#define NB 384
#define ND 256

__global__ __launch_bounds__(256) void triplet_kernel(const float* __restrict__ emb,
                                                      const int* __restrict__ labels,
                                                      float* __restrict__ acc) {
    __shared__ float s_ei[ND];    // emb[i]
    __shared__ float s_row[NB];   // pdist row i
    __shared__ int   s_lab[NB];
    __shared__ float s_red[8];    // 4 waves x {sum, cnt}

    const int i   = blockIdx.x;
    const int tid = threadIdx.x;

    // stage emb[i] (256 floats) and labels (384 ints)
    s_ei[tid]  = emb[i * ND + tid];
    s_lab[tid] = labels[tid];
    if (tid < NB - 256) s_lab[256 + tid] = labels[256 + tid];
    __syncthreads();

    // compute pdist row i: d(i,j) for all j
    for (int j = tid; j < NB; j += 256) {
        const float4* ej = (const float4*)(emb + (size_t)j * ND);
        float d2 = 0.f;
        #pragma unroll 8
        for (int d4 = 0; d4 < ND / 4; ++d4) {
            float4 v = ej[d4];
            float a0 = s_ei[d4 * 4 + 0] - v.x;
            float a1 = s_ei[d4 * 4 + 1] - v.y;
            float a2 = s_ei[d4 * 4 + 2] - v.z;
            float a3 = s_ei[d4 * 4 + 3] - v.w;
            d2 = fmaf(a0, a0, d2);
            d2 = fmaf(a1, a1, d2);
            d2 = fmaf(a2, a2, d2);
            d2 = fmaf(a3, a3, d2);
        }
        s_row[j] = (d2 > 0.f) ? sqrtf(d2) : 0.f;
    }
    __syncthreads();

    const int li = s_lab[i];
    float sum = 0.f, cnt = 0.f;
    for (int j = 0; j < NB; ++j) {
        // wave-uniform filter: positives only (same label, j != i)
        if (s_lab[j] != li || j == i) continue;
        const float ap = s_row[j] + MARGIN;
        for (int k = tid; k < NB; k += 256) {
            if (s_lab[k] == li) continue;     // negatives only
            float v = ap - s_row[k];
            if (v > 0.f)     sum += v;
            if (v > 1e-16f)  cnt += 1.f;
        }
    }

    // wave reduction (64-wide), then cross-wave via LDS
    #pragma unroll
    for (int off = 32; off > 0; off >>= 1) {
        sum += __shfl_down(sum, off, 64);
        cnt += __shfl_down(cnt, off, 64);
    }
    const int wave = tid >> 6;
    if ((tid & 63) == 0) { s_red[wave] = sum; s_red[4 + wave] = cnt; }
    __syncthreads();
    if (tid == 0) {
        float ts = s_red[0] + s_red[1] + s_red[2] + s_red[3];
        float tc = s_red[4] + s_red[5] + s_red[6] + s_red[7];
        atomicAdd(&acc[0], ts);
        atomicAdd(&acc[1], tc);
    }
}

__global__ void finalize_kernel(const float* __restrict__ acc, float* __restrict__ out) {
    out[0] = acc[0] / (acc[1] + 1e-16f);
}

extern "C" void kernel_launch(void* const* d_in, const int* in_sizes, int n_in,
                              void* d_out, int out_size, void* d_ws, size_t ws_size,
                              hipStream_t stream) {
    const float* emb    = (const float*)d_in[0];
    const int*   labels = (const int*)d_in[1];
    float*       out    = (float*)d_out;
    float*       acc    = (float*)d_ws;

    hipMemsetAsync(acc, 0, 2 * sizeof(float), stream);
    triplet_kernel<<<NB, 256, 0, stream>>>(emb, labels, acc);
    finalize_kernel<<<1, 1, 0, stream>>>(acc, out);
}

// Round 2
// 39.400 us; speedup vs baseline: 1.5150x; 1.5150x over previous
//
#include <hip/hip_runtime.h>
#include <math.h>

#define MARGIN 5.0f
#define NB 384
#define ND 256
#define TS 32

// ---------- prep: embT[d][j] = emb[j][d] ----------
__global__ __launch_bounds__(256) void transpose_kernel(const float* __restrict__ emb,
                                                        float* __restrict__ embT) {
    __shared__ float tile[TS][TS + 1];
    const int jt = blockIdx.x * TS;           // j tile (12)
    const int dt = blockIdx.y * TS;           // d tile (8)
    const int tx = threadIdx.x & 31;
    const int ty = threadIdx.x >> 5;          // 0..7
    #pragma unroll
    for (int k = 0; k < 4; ++k)
        tile[ty + 8 * k][tx] = emb[(size_t)(jt + ty + 8 * k) * ND + dt + tx];
    __syncthreads();
    #pragma unroll
    for (int k = 0; k < 4; ++k)
        embT[(size_t)(dt + ty + 8 * k) * NB + jt + tx] = tile[tx][ty + 8 * k];
}

// ---------- main: one block per anchor i, thread t owns j=t ----------
__global__ __launch_bounds__(384) void triplet_kernel(const float* __restrict__ emb,
                                                      const float* __restrict__ embT,
                                                      const int* __restrict__ labels,
                                                      float* __restrict__ acc,
                                                      float* __restrict__ out) {
    __shared__ float s_row[NB];
    __shared__ int   s_plist[64];
    __shared__ int   s_cnt;
    __shared__ float s_red[12];               // 6 waves x {sum,cnt}

    const int i = blockIdx.x;
    const int t = threadIdx.x;
    if (t == 0) s_cnt = 0;

    // distance d(i,t): coalesced embT column walk + wave-uniform emb[i] reads
    const float* __restrict__ ecol = embT + t;
    const float* __restrict__ ei   = emb + (size_t)i * ND;
    float d2 = 0.f;
    #pragma unroll 8
    for (int d = 0; d < ND; ++d) {
        float e  = ei[d];                     // uniform -> scalar load
        float v  = ecol[(size_t)d * NB];      // coalesced across t
        float df = e - v;
        d2 = fmaf(df, df, d2);
    }
    const float r1 = sqrtf(d2);
    s_row[t] = r1;

    const int li  = labels[i];                // uniform
    const int lt  = labels[t];                // coalesced
    const bool neg = (lt != li);

    __syncthreads();                          // s_cnt init + s_row visible

    if (!neg && t != i) {
        int p = atomicAdd(&s_cnt, 1);
        if (p < 64) s_plist[p] = t;
    }
    __syncthreads();                          // plist visible

    const int np = (s_cnt < 64) ? s_cnt : 64;
    float sum = 0.f, cnt = 0.f;
    if (neg) {
        for (int p = 0; p < np; ++p) {
            float ap = s_row[s_plist[p]] + MARGIN;   // LDS broadcast
            float v  = ap - r1;
            if (v > 0.f)    sum += v;
            if (v > 1e-16f) cnt += 1.f;
        }
    }

    // block reduction: 6 waves
    #pragma unroll
    for (int off = 32; off; off >>= 1) {
        sum += __shfl_xor(sum, off, 64);
        cnt += __shfl_xor(cnt, off, 64);
    }
    const int w = t >> 6;
    if ((t & 63) == 0) { s_red[w] = sum; s_red[6 + w] = cnt; }
    __syncthreads();

    if (t == 0) {
        float ts = 0.f, tc = 0.f;
        #pragma unroll
        for (int q = 0; q < 6; ++q) { ts += s_red[q]; tc += s_red[6 + q]; }
        atomicAdd(&acc[0], ts);
        atomicAdd(&acc[1], tc);
        __threadfence();
        unsigned old = atomicAdd((unsigned int*)(acc + 2), 1u);
        if (old == (unsigned)gridDim.x - 1u) {     // last block finalizes
            volatile float* va = acc;
            out[0] = va[0] / (va[1] + 1e-16f);
        }
    }
}

extern "C" void kernel_launch(void* const* d_in, const int* in_sizes, int n_in,
                              void* d_out, int out_size, void* d_ws, size_t ws_size,
                              hipStream_t stream) {
    const float* emb    = (const float*)d_in[0];
    const int*   labels = (const int*)d_in[1];
    float*       out    = (float*)d_out;

    float* embT = (float*)d_ws;                              // 256*384*4 = 393216 B
    float* acc  = (float*)((char*)d_ws + (size_t)ND * NB * 4); // [sum, cnt, counter, pad]

    hipMemsetAsync(acc, 0, 16, stream);
    dim3 tgrid(NB / TS, ND / TS);
    transpose_kernel<<<tgrid, 256, 0, stream>>>(emb, embT);
    triplet_kernel<<<NB, 384, 0, stream>>>(emb, embT, labels, acc, out);
}

// Round 3
// 25.450 us; speedup vs baseline: 2.3455x; 1.5481x over previous
//
#include <hip/hip_runtime.h>
#include <math.h>

#define MARGIN 5.0f
#define NB 384
#define ND 256
#define TS 32

// ---------- prep: embT[d][j] = emb[j][d] ----------
__global__ __launch_bounds__(256) void transpose_kernel(const float* __restrict__ emb,
                                                        float* __restrict__ embT) {
    __shared__ float tile[TS][TS + 1];
    const int jt = blockIdx.x * TS;           // j tile (12)
    const int dt = blockIdx.y * TS;           // d tile (8)
    const int tx = threadIdx.x & 31;
    const int ty = threadIdx.x >> 5;          // 0..7
    #pragma unroll
    for (int k = 0; k < 4; ++k)
        tile[ty + 8 * k][tx] = emb[(size_t)(jt + ty + 8 * k) * ND + dt + tx];
    __syncthreads();
    #pragma unroll
    for (int k = 0; k < 4; ++k)
        embT[(size_t)(dt + ty + 8 * k) * NB + jt + tx] = tile[tx][ty + 8 * k];
}

// ---------- main: one block per anchor i, thread t owns j=t ----------
// Writes per-block partials {sum, cnt} -> no init, no atomics.
__global__ __launch_bounds__(384) void triplet_kernel(const float* __restrict__ emb,
                                                      const float* __restrict__ embT,
                                                      const int* __restrict__ labels,
                                                      float* __restrict__ partial) {
    __shared__ float s_row[NB];
    __shared__ int   s_plist[64];
    __shared__ int   s_cnt;
    __shared__ float s_red[12];               // 6 waves x {sum,cnt}

    const int i = blockIdx.x;
    const int t = threadIdx.x;
    if (t == 0) s_cnt = 0;

    // distance d(i,t): coalesced embT column walk + wave-uniform emb[i] reads
    const float* __restrict__ ecol = embT + t;
    const float* __restrict__ ei   = emb + (size_t)i * ND;
    float d2 = 0.f;
    #pragma unroll 8
    for (int d = 0; d < ND; ++d) {
        float e  = ei[d];                     // uniform -> scalar load
        float v  = ecol[(size_t)d * NB];      // coalesced across t
        float df = e - v;
        d2 = fmaf(df, df, d2);
    }
    const float r1 = sqrtf(d2);
    s_row[t] = r1;

    const int li  = labels[i];                // uniform
    const int lt  = labels[t];                // coalesced
    const bool neg = (lt != li);

    __syncthreads();                          // s_cnt init + s_row visible

    if (!neg && t != i) {
        int p = atomicAdd(&s_cnt, 1);
        if (p < 64) s_plist[p] = t;
    }
    __syncthreads();                          // plist visible

    const int np = (s_cnt < 64) ? s_cnt : 64;
    float sum = 0.f, cnt = 0.f;
    if (neg) {
        for (int p = 0; p < np; ++p) {
            float ap = s_row[s_plist[p]] + MARGIN;   // LDS broadcast
            float v  = ap - r1;
            if (v > 0.f)    sum += v;
            if (v > 1e-16f) cnt += 1.f;
        }
    }

    // block reduction: 6 waves
    #pragma unroll
    for (int off = 32; off; off >>= 1) {
        sum += __shfl_xor(sum, off, 64);
        cnt += __shfl_xor(cnt, off, 64);
    }
    const int w = t >> 6;
    if ((t & 63) == 0) { s_red[w] = sum; s_red[6 + w] = cnt; }
    __syncthreads();

    if (t == 0) {
        float ts = 0.f, tc = 0.f;
        #pragma unroll
        for (int q = 0; q < 6; ++q) { ts += s_red[q]; tc += s_red[6 + q]; }
        partial[2 * i]     = ts;
        partial[2 * i + 1] = tc;
    }
}

// ---------- final: sum 384 partial pairs, write scalar ----------
__global__ __launch_bounds__(384) void reduce_kernel(const float* __restrict__ partial,
                                                     float* __restrict__ out) {
    __shared__ float s_red[12];
    const int t = threadIdx.x;
    float sum = partial[2 * t];
    float cnt = partial[2 * t + 1];
    #pragma unroll
    for (int off = 32; off; off >>= 1) {
        sum += __shfl_xor(sum, off, 64);
        cnt += __shfl_xor(cnt, off, 64);
    }
    const int w = t >> 6;
    if ((t & 63) == 0) { s_red[w] = sum; s_red[6 + w] = cnt; }
    __syncthreads();
    if (t == 0) {
        float ts = 0.f, tc = 0.f;
        #pragma unroll
        for (int q = 0; q < 6; ++q) { ts += s_red[q]; tc += s_red[6 + q]; }
        out[0] = ts / (tc + 1e-16f);
    }
}

extern "C" void kernel_launch(void* const* d_in, const int* in_sizes, int n_in,
                              void* d_out, int out_size, void* d_ws, size_t ws_size,
                              hipStream_t stream) {
    const float* emb    = (const float*)d_in[0];
    const int*   labels = (const int*)d_in[1];
    float*       out    = (float*)d_out;

    float* embT    = (float*)d_ws;                                   // 393216 B
    float* partial = (float*)((char*)d_ws + (size_t)ND * NB * 4);    // 384*2*4 B

    dim3 tgrid(NB / TS, ND / TS);
    transpose_kernel<<<tgrid, 256, 0, stream>>>(emb, embT);
    triplet_kernel<<<NB, 384, 0, stream>>>(emb, embT, labels, partial);
    reduce_kernel<<<1, 384, 0, stream>>>(partial, out);
}